// Round 4
// baseline (608.332 us; speedup 1.0000x reference)
//
#include <hip/hip_runtime.h>

// QRNN: y = inp @ W^T + b -> z=tanh(y0), f=sig(y1), o=sig(y2)
//       h_t = f*z + (1-f)*h;  out0 = sig(o)*h [B,S,H];  out1 = h_{S-1} [B,H]
// Established: inputs fp32, output fp32; gates stored ACTIVATED (r5);
//   fp16 gates (r8): absmax unchanged 0.0078125, -536 MB traffic.
// r7 post-mortem: XCD swizzle thrashes L2 on W (6.3MB > 4MB) -> identity order.
// r9 (this round): GEMM was at the m97-structure ceiling (752 TF, MfmaUtil 35%,
//   VALUBusy 66%, 16 K-tiles each ending in a full vmcnt(0) drain). Rewrite as
//   the 256^2 8-phase schedule (T2+T3+T4+T5, m201: 1563 TF @4k):
//   - 512 thr (8 waves 2Mx4N), per-wave C = 128x64, BK=64, NT=16
//   - LDS 128KB: 2 buffers x (A 256x64 + B 256x64) bf16, XOR-swizzled via
//     pre-swizzled GLOBAL source + linear gload_lds dest (rule #21, verified)
//   - raw s_barrier phases; counted s_waitcnt vmcnt(4) ONCE per K-tile
//     (never 0 in the loop) -- T4, the proven lever (+38-73%, m218)
//   - half-tile stage schedule per tile t: ph0 hA0(t+1), ph1 hA1(t+1),
//     ph2 hB0(t+2), ph3 hB1(t+2). Lifetimes verified: B-reads of tile t done
//     by ph1-end barrier, A-reads by ph2-end; t+1 goes to the other buffer;
//     boundary vmcnt(4) = exactly the 2 newest half-tiles may be in flight.
//   - s_setprio(1) around each 16-MFMA quad (T5)

typedef unsigned short ushort_t;
typedef _Float16 half_t;
typedef __bf16 bf16x8 __attribute__((ext_vector_type(8)));
typedef float f32x4 __attribute__((ext_vector_type(4)));
typedef ushort_t us8 __attribute__((ext_vector_type(8)));
typedef half_t f16x4 __attribute__((ext_vector_type(4)));

#define BAR()                                   \
  do {                                          \
    asm volatile("" ::: "memory");              \
    __builtin_amdgcn_s_barrier();               \
    asm volatile("" ::: "memory");              \
  } while (0)
#define WAIT_VMCNT(N) asm volatile("s_waitcnt vmcnt(" #N ")" ::: "memory")

__device__ __forceinline__ ushort_t f2bf(float f) {
  unsigned int x = __builtin_bit_cast(unsigned int, f);
  x += 0x7fffu + ((x >> 16) & 1u);  // RNE
  return (ushort_t)(x >> 16);
}
__device__ __forceinline__ float bf2f(ushort_t u) {
  unsigned int x = ((unsigned int)u) << 16;
  return __builtin_bit_cast(float, x);
}
__device__ __forceinline__ void storeg(float* p, float v) { *p = v; }
__device__ __forceinline__ void storeg(half_t* p, float v) { *p = (half_t)v; }

__device__ __forceinline__ f32x4 loadg4(const float* p) {
  return *(const f32x4*)p;
}
__device__ __forceinline__ f32x4 loadg4(const half_t* p) {
  const f16x4 v = *(const f16x4*)p;  // 8B load
  f32x4 r;
  r[0] = (float)v[0]; r[1] = (float)v[1]; r[2] = (float)v[2]; r[3] = (float)v[3];
  return r;
}
__device__ __forceinline__ f32x4 fma4(f32x4 a, f32x4 b, f32x4 c) {
  f32x4 r;
#pragma unroll
  for (int k = 0; k < 4; ++k) r[k] = fmaf(a[k], b[k], c[k]);
  return r;
}

__device__ __forceinline__ float sig_f(float x) { return 1.0f / (1.0f + __expf(-x)); }
__device__ __forceinline__ float tanh_f(float x) { return 1.0f - 2.0f / (1.0f + __expf(2.0f * x)); }

// async global->LDS, 16B per lane; LDS dest = WAVE-UNIFORM base + lane*16.
__device__ __forceinline__ void gload_lds16(const ushort_t* g, ushort_t* l) {
  __builtin_amdgcn_global_load_lds(
      (const __attribute__((address_space(1))) void*)g,
      (__attribute__((address_space(3))) void*)l, 16, 0, 0);
}

// ---------------- K0: fp32 -> bf16 pre-convert (RNE) ----------------
__global__ void __launch_bounds__(256) cvt_f32_bf16(
    const float* __restrict__ in, ushort_t* __restrict__ out, long n8) {
  long i = (long)blockIdx.x * 256 + threadIdx.x;
  const long stride = (long)gridDim.x * 256;
  for (; i < n8; i += stride) {
    const float4 a = ((const float4*)in)[2 * i];
    const float4 c = ((const float4*)in)[2 * i + 1];
    us8 w;
    w[0] = f2bf(a.x); w[1] = f2bf(a.y); w[2] = f2bf(a.z); w[3] = f2bf(a.w);
    w[4] = f2bf(c.x); w[5] = f2bf(c.y); w[6] = f2bf(c.z); w[7] = f2bf(c.w);
    ((us8*)out)[i] = w;
  }
}

// ---------------- K1: 256^2 8-phase GEMM + activation epilogue ----------------
// A [M,K] bf16, Wt [N,K] bf16 (B^T layout), out [M,N] ACTIVATED gates (fp16).
// LDS row layout: row r (0..255) x 8 slots of 16B; slot s holds global
// k-group s ^ (r&7)  (staged by pre-swizzled source; read with same XOR).
template <typename GT>
__global__ void __launch_bounds__(512, 2) gemm_gates(
    const ushort_t* __restrict__ A, const ushort_t* __restrict__ Wt,
    const float* __restrict__ bias, GT* __restrict__ out,
    int M, int N, int K) {
  constexpr int BK = 64;
  constexpr int TILE = 256 * BK;                   // ushorts per matrix buffer
  __shared__ __align__(16) ushort_t As[2 * TILE];  // 64 KB
  __shared__ __align__(16) ushort_t Bs[2 * TILE];  // 64 KB
  const int tid = threadIdx.x;
  const int lane = tid & 63;
  const int wv = tid >> 6;  // 0..7
  const int nblk = N >> 8;
  const int bm = blockIdx.x / nblk, bn = blockIdx.x % nblk;
  const int m0 = bm << 8, n0 = bn << 8;
  const int wm = (wv >> 2) << 7;  // 0 or 128
  const int wn = (wv & 3) << 6;   // 0,64,128,192
  const int NT = K >> 6;          // 16

  // staging lane geometry: 8 rows x 8 slots of 16B per wave-issue
  const int srow = lane >> 3;        // 0..7
  const int sg = (lane & 7) ^ srow;  // pre-swizzled global 16B k-group
  const ushort_t* Ag = A + (size_t)m0 * K;
  const ushort_t* Wg = Wt + (size_t)n0 * K;

  // fragment-read geometry (16x16x32): row-in-frag + swizzled slots per ks
  const int fr = lane & 15;
  const int sl0 = ((lane >> 4) + 0) ^ (lane & 7);
  const int sl1 = ((lane >> 4) + 4) ^ (lane & 7);

  f32x4 acc[8][4] = {};
  bf16x8 af[4][2], b0r[2][2], b1r[2][2];

  auto stage_half = [&](const ushort_t* gbase, int row0, ushort_t* lds, int kt) {
#pragma unroll
    for (int rnd = 0; rnd < 2; ++rnd) {
      const int rb = row0 + rnd * 64 + wv * 8;  // wave-uniform
      gload_lds16(&gbase[(size_t)(rb + srow) * K + kt + sg * 8], &lds[rb * 64]);
    }
  };
  auto loadA = [&](const ushort_t* Ab, int mi) {
#pragma unroll
    for (int mf = 0; mf < 4; ++mf) {
      const int row = wm + (mi * 4 + mf) * 16 + fr;
      af[mf][0] = *(const bf16x8*)&Ab[row * 64 + sl0 * 8];
      af[mf][1] = *(const bf16x8*)&Ab[row * 64 + sl1 * 8];
    }
  };
  auto loadB = [&](bf16x8 (&br)[2][2], const ushort_t* Bb, int ni) {
#pragma unroll
    for (int nf = 0; nf < 2; ++nf) {
      const int row = wn + (ni * 2 + nf) * 16 + fr;
      br[nf][0] = *(const bf16x8*)&Bb[row * 64 + sl0 * 8];
      br[nf][1] = *(const bf16x8*)&Bb[row * 64 + sl1 * 8];
    }
  };
  auto quad = [&](bf16x8 (&br)[2][2], int mi, int ni) {
    __builtin_amdgcn_s_setprio(1);
#pragma unroll
    for (int mf = 0; mf < 4; ++mf)
#pragma unroll
      for (int nf = 0; nf < 2; ++nf)
#pragma unroll
        for (int ks = 0; ks < 2; ++ks)
          acc[mi * 4 + mf][ni * 2 + nf] = __builtin_amdgcn_mfma_f32_16x16x32_bf16(
              af[mf][ks], br[nf][ks], acc[mi * 4 + mf][ni * 2 + nf], 0, 0, 0);
    __builtin_amdgcn_s_setprio(0);
  };

  // prologue: tile0 {A0,A1,B0,B1} (8 loads), tile1 {B0,B1} (4 loads)
  stage_half(Ag, 0, As, 0);
  stage_half(Ag, 128, As, 0);
  stage_half(Wg, 0, Bs, 0);
  stage_half(Wg, 128, Bs, 0);
  if (NT > 1) {
    stage_half(Wg, 0, Bs + TILE, BK);
    stage_half(Wg, 128, Bs + TILE, BK);
    WAIT_VMCNT(4);  // tile0's 8 landed; tile1's B halves may be in flight
  } else {
    WAIT_VMCNT(0);
  }
  BAR();

  for (int t = 0; t < NT; ++t) {
    ushort_t* Ab = As + (t & 1) * TILE;
    ushort_t* Bb = Bs + (t & 1) * TILE;
    ushort_t* An = As + ((t & 1) ^ 1) * TILE;
    const int kt1 = (t + 1) * BK, kt2 = (t + 2) * BK;
    const bool s1 = (t + 1 < NT), s2 = (t + 2 < NT);

    // ph0: A mi=0 (8 ds) + B ni=0 (4 ds); stage hA0(t+1) -> other buffer
    loadA(Ab, 0);
    loadB(b0r, Bb, 0);
    if (s1) stage_half(Ag, 0, An, kt1);
    BAR();
    quad(b0r, 0, 0);
    BAR();
    // ph1: B ni=1 (4 ds); stage hA1(t+1)
    loadB(b1r, Bb, 1);
    if (s1) stage_half(Ag, 128, An, kt1);
    BAR();
    quad(b1r, 0, 1);
    BAR();
    // ph2: A mi=1 (8 ds); stage hB0(t+2) -> THIS buffer's B (reads done ph1)
    loadA(Ab, 1);
    if (s2) stage_half(Wg, 0, Bb, kt2);
    BAR();
    quad(b1r, 1, 1);
    BAR();
    // ph3: no ds (reuse b0r regs); stage hB1(t+2); counted boundary wait
    if (s2) stage_half(Wg, 128, Bb, kt2);
    BAR();
    quad(b0r, 1, 0);
    if (s2) {
      WAIT_VMCNT(4);  // tile t+1 fully landed; t+2's 2 B-halves may fly
    } else {
      WAIT_VMCNT(0);  // tail: drain (once)
    }
    BAR();
  }

  // Epilogue. C/D layout (m89/m91): col = lane&15, row = (lane>>4)*4 + reg.
  const int gcat = n0 >> 10;  // 0:z(tanh) 1:f(sig) 2:o(sig); uniform per block
  const int cn = lane & 15;
  const int cm = (lane >> 4) << 2;
#pragma unroll
  for (int j = 0; j < 4; ++j) {
    const int n = n0 + wn + j * 16 + cn;
    const float bv = bias[n];
#pragma unroll
    for (int i = 0; i < 8; ++i) {
#pragma unroll
      for (int r = 0; r < 4; ++r) {
        const int m = m0 + wm + i * 16 + cm + r;
        const float y = acc[i][j][r] + bv;
        const float v = (gcat == 0) ? tanh_f(y) : sig_f(y);
        storeg(&out[(size_t)m * N + n], v);
      }
    }
  }
}

// ---------------- K2: chunk aggregates (4 channels/thread) ----------------
// h_t = f*z + (1-f)*h == g*h + a, g=1-f, a=f*z. Chunk: h_end = Aa + G*h_in.
template <typename GT>
__global__ void __launch_bounds__(256) qrnn_chunk_agg(
    const GT* __restrict__ gates, float* __restrict__ aggG,
    float* __restrict__ aggA, int b0, int S, int H, int C, int L) {
  const int nhb = H >> 10;
  const int hb = blockIdx.x % nhb;
  const int c = (blockIdx.x / nhb) % C;
  const int bl = blockIdx.x / (nhb * C);  // local batch within group
  const int h = (hb << 10) + threadIdx.x * 4;
  const int N3 = 3 * H;
  const GT* pz = gates + ((size_t)(bl * S + c * L)) * N3 + h;
  const GT* pf = pz + H;
  f32x4 G = {1.0f, 1.0f, 1.0f, 1.0f};
  f32x4 Aa = {0.0f, 0.0f, 0.0f, 0.0f};
#pragma unroll 4
  for (int j = 0; j < L; ++j) {
    const f32x4 z = loadg4(pz);
    const f32x4 f = loadg4(pf);
    const f32x4 g = 1.0f - f;
    Aa = fma4(g, Aa, f * z);
    G *= g;
    pz += N3;
    pf += N3;
  }
  const size_t idx = ((size_t)((b0 + bl) * C + c)) * H + h;
  *(f32x4*)&aggG[idx] = G;
  *(f32x4*)&aggA[idx] = Aa;
}

// ---------------- K3: prefix fold + replay + output gate ----------------
template <typename GT>
__global__ void __launch_bounds__(256) qrnn_scan_apply(
    const GT* __restrict__ gates, const float* __restrict__ aggG,
    const float* __restrict__ aggA, float* __restrict__ out,
    int b0, int B, int S, int H, int C, int L) {
  const int nhb = H >> 10;
  const int hb = blockIdx.x % nhb;
  const int c = (blockIdx.x / nhb) % C;
  const int bl = blockIdx.x / (nhb * C);
  const int bg = b0 + bl;  // global batch
  const int h = (hb << 10) + threadIdx.x * 4;
  const int N3 = 3 * H;

  f32x4 hc = {0.0f, 0.0f, 0.0f, 0.0f};  // h at chunk start (c uniform)
  for (int cc = 0; cc < c; ++cc) {
    const size_t idx = ((size_t)(bg * C + cc)) * H + h;
    hc = fma4(*(const f32x4*)&aggG[idx], hc, *(const f32x4*)&aggA[idx]);
  }

  const GT* pz = gates + ((size_t)(bl * S + c * L)) * N3 + h;
  const GT* pf = pz + H;
  const GT* po = pf + H;
  size_t oidx = ((size_t)(bg * S + c * L)) * H + h;
#pragma unroll 4
  for (int j = 0; j < L; ++j) {
    const f32x4 z = loadg4(pz);
    const f32x4 f = loadg4(pf);
    const f32x4 o = loadg4(po);  // already sigmoid(y_o)
    hc = fma4(1.0f - f, hc, f * z);
    *(f32x4*)&out[oidx] = o * hc;
    pz += N3; pf += N3; po += N3; oidx += H;
  }
  if (c == C - 1) {  // final state c[:, -1] -> second output [B,H]
    *(f32x4*)&out[(size_t)B * S * H + (size_t)bg * H + h] = hc;
  }
}

template <typename GT>
static void run_groups(const float* inp, const ushort_t* Wbf, const float* b,
                       float* out, ushort_t* Abf, void* gates_ws, float* aggG,
                       float* aggA, int Bg, int B, int S, int H, int K, int C,
                       int L, hipStream_t stream) {
  const int N = 3 * H;
  GT* gates = (GT*)gates_ws;
  for (int b0 = 0; b0 < B; b0 += Bg) {
    const int Mg = Bg * S;
    const long n8 = (long)Mg * K / 8;
    const long cg = (n8 + 255) / 256;
    const int cgrid = (int)(cg < 2048 ? cg : 2048);
    cvt_f32_bf16<<<cgrid, 256, 0, stream>>>(inp + (size_t)b0 * S * K, Abf, n8);
    const int gemm_grid = (Mg / 256) * (N / 256);
    const int scan_grid = Bg * C * (H / 1024);
    gemm_gates<GT><<<gemm_grid, 512, 0, stream>>>(Abf, Wbf, b, gates, Mg, N, K);
    qrnn_chunk_agg<GT><<<scan_grid, 256, 0, stream>>>(
        gates, aggG, aggA, b0, S, H, C, L);
    qrnn_scan_apply<GT><<<scan_grid, 256, 0, stream>>>(
        gates, aggG, aggA, out, b0, B, S, H, C, L);
  }
}

extern "C" void kernel_launch(void* const* d_in, const int* in_sizes, int n_in,
                              void* d_out, int out_size, void* d_ws, size_t ws_size,
                              hipStream_t stream) {
  (void)in_sizes; (void)n_in; (void)out_size;
  const float* inp = (const float*)d_in[0];  // [B,S,D] fp32
  const float* W = (const float*)d_in[1];    // [3H,D] fp32
  const float* b = (const float*)d_in[2];    // [3H] fp32
  float* out = (float*)d_out;                // [B,S,H] ++ [B,H] fp32

  constexpr int B = 16, S = 2048, H = 1024, K = 1024;
  constexpr int C = 64, L = S / C;
  const int N3 = 3 * H;

  // ws layout: [aggG fp32 B*C*H][aggA fp32 B*C*H][Wbf bf16 3H*K]
  //            [Abf bf16 Bg*S*K][gates fp16 (group-local)]
  const size_t agg_elems = (size_t)B * C * H;
  float* aggG = (float*)d_ws;
  float* aggA = aggG + agg_elems;
  ushort_t* Wbf = (ushort_t*)(aggA + agg_elems);
  ushort_t* Abf = Wbf + (size_t)N3 * K;
  const size_t hdr =
      2 * agg_elems * sizeof(float) + (size_t)N3 * K * sizeof(ushort_t);

  // Largest batch-group whose (Abf + fp16 gates) fit.
  int Bg = 0;
  for (int g = 16; g >= 1; g >>= 1) {
    const size_t need = hdr + (size_t)g * S * K * sizeof(ushort_t) +
                        (size_t)g * S * N3 * sizeof(half_t);
    if (need <= ws_size) { Bg = g; break; }
  }
  if (!Bg) return;
  void* gates_ws = (void*)(Abf + (size_t)Bg * S * K);

  // Convert W once (RNE, identical numerics to the in-GEMM convert).
  {
    const long n8w = (long)N3 * K / 8;
    const long cg = (n8w + 255) / 256;
    const int grid = (int)(cg < 2048 ? cg : 2048);
    cvt_f32_bf16<<<grid, 256, 0, stream>>>(W, Wbf, n8w);
  }

  run_groups<half_t>(inp, Wbf, b, out, Abf, gates_ws, aggG, aggA, Bg,
                     B, S, H, K, C, L, stream);
}

// Round 5
// 590.377 us; speedup vs baseline: 1.0304x; 1.0304x over previous
//
#include <hip/hip_runtime.h>

// QRNN: y = inp @ W^T + b -> z=tanh(y0), f=sig(y1), o=sig(y2)
//       h_t = f*z + (1-f)*h;  out0 = sig(o)*h [B,S,H];  out1 = h_{S-1} [B,H]
// Established: inputs fp32, output fp32; gates stored ACTIVATED (r5);
//   fp16 gates (r8): absmax unchanged 0.0078125, -536 MB traffic.
// r7: XCD swizzle thrashes L2 on W (6.3MB > 4MB) -> identity block order.
// r9 post-mortem: 8-phase 256^2 REGRESSED here (303us, MfmaUtil 29%, all
//   pipes low): NT=16 K-tiles amortizes prologue/epilogue 4x worse than
//   m201's 4k benchmark, and 128KB LDS -> 1 block/CU -> nothing to overlap
//   barrier stalls. REVERTED to r8's 128^2 m97-structure (proven 274us).
// r10 (this round): scans had ~190us slack (~275us vs ~85 ideal).
//   (a) K3's per-block prefix fold = C^2/2 redundant agg traffic (~258MB
//       L2/L3) + serial preamble -> new tiny qrnn_prefix kernel computes
//       aggH[b,c] once; K3 starts from one 16B read.
//   (b) C 64->128 (L=16): scan grid 1024->2048 blocks, 2x waves/CU ->
//       2x loads in flight for the latency-bound gate stream.
//   (c) K3 out-writes (never re-read) -> nontemporal stores.

typedef unsigned short ushort_t;
typedef _Float16 half_t;
typedef __bf16 bf16x8 __attribute__((ext_vector_type(8)));
typedef float f32x4 __attribute__((ext_vector_type(4)));
typedef ushort_t us8 __attribute__((ext_vector_type(8)));
typedef half_t f16x4 __attribute__((ext_vector_type(4)));

__device__ __forceinline__ ushort_t f2bf(float f) {
  unsigned int x = __builtin_bit_cast(unsigned int, f);
  x += 0x7fffu + ((x >> 16) & 1u);  // RNE
  return (ushort_t)(x >> 16);
}
__device__ __forceinline__ float bf2f(ushort_t u) {
  unsigned int x = ((unsigned int)u) << 16;
  return __builtin_bit_cast(float, x);
}
__device__ __forceinline__ void storeg(float* p, float v) { *p = v; }
__device__ __forceinline__ void storeg(half_t* p, float v) { *p = (half_t)v; }

__device__ __forceinline__ f32x4 loadg4(const float* p) {
  return *(const f32x4*)p;
}
__device__ __forceinline__ f32x4 loadg4(const half_t* p) {
  const f16x4 v = *(const f16x4*)p;  // 8B load
  f32x4 r;
  r[0] = (float)v[0]; r[1] = (float)v[1]; r[2] = (float)v[2]; r[3] = (float)v[3];
  return r;
}
__device__ __forceinline__ f32x4 fma4(f32x4 a, f32x4 b, f32x4 c) {
  f32x4 r;
#pragma unroll
  for (int k = 0; k < 4; ++k) r[k] = fmaf(a[k], b[k], c[k]);
  return r;
}
__device__ __forceinline__ void store4_nt(float* p, f32x4 v) {
  __builtin_nontemporal_store(v, (f32x4*)p);
}

__device__ __forceinline__ float sig_f(float x) { return 1.0f / (1.0f + __expf(-x)); }
__device__ __forceinline__ float tanh_f(float x) { return 1.0f - 2.0f / (1.0f + __expf(2.0f * x)); }

// async global->LDS, 16B per lane; LDS dest = WAVE-UNIFORM base + lane*16.
__device__ __forceinline__ void gload_lds16(const ushort_t* g, ushort_t* l) {
  __builtin_amdgcn_global_load_lds(
      (const __attribute__((address_space(1))) void*)g,
      (__attribute__((address_space(3))) void*)l, 16, 0, 0);
}

// ---------------- K0: fp32 -> bf16 pre-convert (RNE) ----------------
__global__ void __launch_bounds__(256) cvt_f32_bf16(
    const float* __restrict__ in, ushort_t* __restrict__ out, long n8) {
  long i = (long)blockIdx.x * 256 + threadIdx.x;
  const long stride = (long)gridDim.x * 256;
  for (; i < n8; i += stride) {
    const float4 a = ((const float4*)in)[2 * i];
    const float4 c = ((const float4*)in)[2 * i + 1];
    us8 w;
    w[0] = f2bf(a.x); w[1] = f2bf(a.y); w[2] = f2bf(a.z); w[3] = f2bf(a.w);
    w[4] = f2bf(c.x); w[5] = f2bf(c.y); w[6] = f2bf(c.z); w[7] = f2bf(c.w);
    ((us8*)out)[i] = w;
  }
}

// ---------------- K1: GEMM + activation epilogue (r8 structure) ----------------
// A [M,K] bf16, Wt [N,K] bf16 (B^T layout), out [M,N] ACTIVATED gates (fp16).
// 128x128 tile, BK=64, 4 waves 2x2, each wave 4x4 MFMA 16x16x32 tiles.
// LDS: linear [row][64] bf16 dest for global_load_lds; swizzle realized by
// fetching global k-group (slot ^ (row&7)) -> read path XOR unchanged.
// blockIdx mapping: IDENTITY (r7: XCD swizzle thrashes L2 on W here).
template <typename GT>
__global__ void __launch_bounds__(256) gemm_gates(
    const ushort_t* __restrict__ A, const ushort_t* __restrict__ Wt,
    const float* __restrict__ bias, GT* __restrict__ out,
    int M, int N, int K) {
  constexpr int BK = 64;
  __shared__ __align__(16) ushort_t As[128 * BK];
  __shared__ __align__(16) ushort_t Bs[128 * BK];
  const int tid = threadIdx.x;
  const int lane = tid & 63;
  const int wv = tid >> 6;  // 0..3

  const int bid = blockIdx.x;
  const int nblk = N >> 7;
  const int bn = bid % nblk;
  const int bm = bid / nblk;
  const int m0 = bm << 7, n0 = bn << 7;
  const int wm = (wv >> 1) << 6, wn = (wv & 1) << 6;

  f32x4 acc[4][4] = {};

  // Staging geometry: per wave-issue, 64 lanes cover 8 rows x 8 slots of 16B.
  const int srow = lane >> 3;       // row within 8-row group
  const int sg = (lane & 7) ^ srow; // pre-swizzled global 16B k-group

  for (int kt = 0; kt < K; kt += BK) {
    __syncthreads();
#pragma unroll
    for (int i = 0; i < 4; ++i) {
      const int rbase = wv * 32 + i * 8;  // wave-uniform
      gload_lds16(&A[(size_t)(m0 + rbase + srow) * K + kt + sg * 8],
                  &As[rbase * 64]);
      gload_lds16(&Wt[(size_t)(n0 + rbase + srow) * K + kt + sg * 8],
                  &Bs[rbase * 64]);
    }
    __syncthreads();  // compiler emits vmcnt(0) drain here (m97 structure)
#pragma unroll
    for (int ks = 0; ks < 2; ++ks) {
      bf16x8 af[4], bfr[4];
#pragma unroll
      for (int t = 0; t < 4; ++t) {
        const int ar = wm + t * 16 + (lane & 15);
        const int ag = ((ks << 2) + (lane >> 4)) ^ (ar & 7);
        af[t] = *(const bf16x8*)&As[ar * 64 + ag * 8];
        const int br = wn + t * 16 + (lane & 15);
        const int bg = ((ks << 2) + (lane >> 4)) ^ (br & 7);
        bfr[t] = *(const bf16x8*)&Bs[br * 64 + bg * 8];
      }
#pragma unroll
      for (int i = 0; i < 4; ++i)
#pragma unroll
        for (int j = 0; j < 4; ++j)
          acc[i][j] =
              __builtin_amdgcn_mfma_f32_16x16x32_bf16(af[i], bfr[j], acc[i][j], 0, 0, 0);
    }
  }

  // Epilogue. C/D layout (m89/m91): col = lane&15, row = (lane>>4)*4 + reg.
  const int gcat = n0 >> 10;  // 0:z(tanh) 1:f(sig) 2:o(sig); uniform per block
  const int cn = lane & 15;
  const int cm = (lane >> 4) << 2;
#pragma unroll
  for (int j = 0; j < 4; ++j) {
    const int n = n0 + wn + j * 16 + cn;
    const float bv = bias[n];
#pragma unroll
    for (int i = 0; i < 4; ++i) {
#pragma unroll
      for (int r = 0; r < 4; ++r) {
        const int m = m0 + wm + i * 16 + cm + r;
        const float y = acc[i][j][r] + bv;
        const float v = (gcat == 0) ? tanh_f(y) : sig_f(y);
        storeg(&out[(size_t)m * N + n], v);
      }
    }
  }
}

// ---------------- K2: chunk aggregates (4 channels/thread) ----------------
// h_t = f*z + (1-f)*h == g*h + a, g=1-f, a=f*z. Chunk: h_end = Aa + G*h_in.
// grid: Bg * C * (H/1024); 256 threads, each owns 4 h-channels.
template <typename GT>
__global__ void __launch_bounds__(256) qrnn_chunk_agg(
    const GT* __restrict__ gates, float* __restrict__ aggG,
    float* __restrict__ aggA, int b0, int S, int H, int C, int L) {
  const int nhb = H >> 10;
  const int hb = blockIdx.x % nhb;
  const int c = (blockIdx.x / nhb) % C;
  const int bl = blockIdx.x / (nhb * C);  // local batch within group
  const int h = (hb << 10) + threadIdx.x * 4;
  const int N3 = 3 * H;
  const GT* pz = gates + ((size_t)(bl * S + c * L)) * N3 + h;
  const GT* pf = pz + H;
  f32x4 G = {1.0f, 1.0f, 1.0f, 1.0f};
  f32x4 Aa = {0.0f, 0.0f, 0.0f, 0.0f};
#pragma unroll 4
  for (int j = 0; j < L; ++j) {
    const f32x4 z = loadg4(pz);
    const f32x4 f = loadg4(pf);
    const f32x4 g = 1.0f - f;
    Aa = fma4(g, Aa, f * z);
    G *= g;
    pz += N3;
    pf += N3;
  }
  const size_t idx = ((size_t)((b0 + bl) * C + c)) * H + h;
  *(f32x4*)&aggG[idx] = G;
  *(f32x4*)&aggA[idx] = Aa;
}

// ---------------- K2b: prefix over chunk aggregates ----------------
// aggH[b,c] = h at START of chunk c (fold in chunk order; same math/order
// as the old in-K3 prefix loop -> identical numerics, computed once).
__global__ void __launch_bounds__(256) qrnn_prefix(
    const float* __restrict__ aggG, const float* __restrict__ aggA,
    float* __restrict__ aggH, int b0, int H, int C) {
  const int nhb = H >> 10;
  const int b = b0 + blockIdx.x / nhb;
  const int hb = blockIdx.x % nhb;
  const int h = (hb << 10) + threadIdx.x * 4;
  f32x4 hc = {0.0f, 0.0f, 0.0f, 0.0f};
#pragma unroll 4
  for (int c = 0; c < C; ++c) {
    const size_t idx = ((size_t)(b * C + c)) * H + h;
    *(f32x4*)&aggH[idx] = hc;
    hc = fma4(*(const f32x4*)&aggG[idx], hc, *(const f32x4*)&aggA[idx]);
  }
}

// ---------------- K3: replay chunk + output gate ----------------
// gates hold ACTIVATED z,f,o -> o is used DIRECTLY (no second sigmoid).
template <typename GT>
__global__ void __launch_bounds__(256) qrnn_scan_apply(
    const GT* __restrict__ gates, const float* __restrict__ aggH,
    float* __restrict__ out, int b0, int B, int S, int H, int C, int L) {
  const int nhb = H >> 10;
  const int hb = blockIdx.x % nhb;
  const int c = (blockIdx.x / nhb) % C;
  const int bl = blockIdx.x / (nhb * C);
  const int bg = b0 + bl;  // global batch
  const int h = (hb << 10) + threadIdx.x * 4;
  const int N3 = 3 * H;

  // h at chunk start: precomputed by qrnn_prefix (one 16B read)
  f32x4 hc = *(const f32x4*)&aggH[((size_t)(bg * C + c)) * H + h];

  const GT* pz = gates + ((size_t)(bl * S + c * L)) * N3 + h;
  const GT* pf = pz + H;
  const GT* po = pf + H;
  size_t oidx = ((size_t)(bg * S + c * L)) * H + h;
#pragma unroll 4
  for (int j = 0; j < L; ++j) {
    const f32x4 z = loadg4(pz);
    const f32x4 f = loadg4(pf);
    const f32x4 o = loadg4(po);  // already sigmoid(y_o)
    hc = fma4(1.0f - f, hc, f * z);
    store4_nt(&out[oidx], o * hc);  // out never re-read -> nontemporal
    pz += N3; pf += N3; po += N3; oidx += H;
  }
  if (c == C - 1) {  // final state c[:, -1] -> second output [B,H]
    *(f32x4*)&out[(size_t)B * S * H + (size_t)bg * H + h] = hc;
  }
}

template <typename GT>
static void run_groups(const float* inp, const ushort_t* Wbf, const float* b,
                       float* out, ushort_t* Abf, void* gates_ws, float* aggG,
                       float* aggA, float* aggH, int Bg, int B, int S, int H,
                       int K, int C, int L, hipStream_t stream) {
  const int N = 3 * H;
  GT* gates = (GT*)gates_ws;
  for (int b0 = 0; b0 < B; b0 += Bg) {
    const int Mg = Bg * S;
    const long n8 = (long)Mg * K / 8;
    const long cg = (n8 + 255) / 256;
    const int cgrid = (int)(cg < 2048 ? cg : 2048);
    cvt_f32_bf16<<<cgrid, 256, 0, stream>>>(inp + (size_t)b0 * S * K, Abf, n8);
    const int gemm_grid = (Mg / 128) * (N / 128);
    const int scan_grid = Bg * C * (H / 1024);
    gemm_gates<GT><<<gemm_grid, 256, 0, stream>>>(Abf, Wbf, b, gates, Mg, N, K);
    qrnn_chunk_agg<GT><<<scan_grid, 256, 0, stream>>>(
        gates, aggG, aggA, b0, S, H, C, L);
    qrnn_prefix<<<Bg * (H / 1024), 256, 0, stream>>>(aggG, aggA, aggH, b0, H, C);
    qrnn_scan_apply<GT><<<scan_grid, 256, 0, stream>>>(
        gates, aggH, out, b0, B, S, H, C, L);
  }
}

extern "C" void kernel_launch(void* const* d_in, const int* in_sizes, int n_in,
                              void* d_out, int out_size, void* d_ws, size_t ws_size,
                              hipStream_t stream) {
  (void)in_sizes; (void)n_in; (void)out_size;
  const float* inp = (const float*)d_in[0];  // [B,S,D] fp32
  const float* W = (const float*)d_in[1];    // [3H,D] fp32
  const float* b = (const float*)d_in[2];    // [3H] fp32
  float* out = (float*)d_out;                // [B,S,H] ++ [B,H] fp32

  constexpr int B = 16, S = 2048, H = 1024, K = 1024;
  constexpr int C = 128, L = S / C;  // r10: C 64->128 (L=16)
  const int N3 = 3 * H;

  // ws layout: [aggG][aggA][aggH] fp32 B*C*H each, [Wbf bf16 3H*K]
  //            [Abf bf16 Bg*S*K][gates fp16 (group-local)]
  const size_t agg_elems = (size_t)B * C * H;
  float* aggG = (float*)d_ws;
  float* aggA = aggG + agg_elems;
  float* aggH = aggA + agg_elems;
  ushort_t* Wbf = (ushort_t*)(aggH + agg_elems);
  ushort_t* Abf = Wbf + (size_t)N3 * K;
  const size_t hdr =
      3 * agg_elems * sizeof(float) + (size_t)N3 * K * sizeof(ushort_t);

  // Largest batch-group whose (Abf + fp16 gates) fit.
  int Bg = 0;
  for (int g = 16; g >= 1; g >>= 1) {
    const size_t need = hdr + (size_t)g * S * K * sizeof(ushort_t) +
                        (size_t)g * S * N3 * sizeof(half_t);
    if (need <= ws_size) { Bg = g; break; }
  }
  if (!Bg) return;
  void* gates_ws = (void*)(Abf + (size_t)Bg * S * K);

  // Convert W once (RNE, identical numerics to the in-GEMM convert).
  {
    const long n8w = (long)N3 * K / 8;
    const long cg = (n8w + 255) / 256;
    const int grid = (int)(cg < 2048 ? cg : 2048);
    cvt_f32_bf16<<<grid, 256, 0, stream>>>(W, Wbf, n8w);
  }

  run_groups<half_t>(inp, Wbf, b, out, Abf, gates_ws, aggG, aggA, aggH, Bg,
                     B, S, H, K, C, L, stream);
}